// Round 9
// baseline (82.744 us; speedup 1.0000x reference)
//
#include <hip/hip_runtime.h>
#include <hip/hip_cooperative_groups.h>

namespace cg = cooperative_groups;

using short8 = __attribute__((ext_vector_type(8))) short;
using sh4    = __attribute__((ext_vector_type(4))) short;
using f32x4  = __attribute__((ext_vector_type(4))) float;
using f32x2  = __attribute__((ext_vector_type(2))) float;
typedef unsigned short ushort_t;

constexpr int BB = 2, FF = 8, CIN = 16, COUT = 32, HH = 128, WW = 128;
constexpr int HW   = HH * WW;          // 16384
constexpr int NIMG = BB * FF;          // 16
constexpr int TIL = 16, HALO = 2, LP = 20, NPX = 400;
constexpr int NSLOT = 1024;            // 16 img * 64 tiles
constexpr int WFN = 17 * 2 * 512;      // 17408 ushorts per conv (A-frags)

__device__ const int DOFF[17] = { -42,-41,-40,-39,-38, -18,2,22, 38,39,40,41,42, -22,-2,18, 0 };

__device__ __forceinline__ float leaky(float v) { return v >= 0.f ? v : 0.01f * v; }
__device__ __forceinline__ ushort_t f2bf(float f) {
    unsigned u = __builtin_bit_cast(unsigned, f);
    u = (u + 0x7FFFu + ((u >> 16) & 1u)) >> 16;
    return (ushort_t)u;
}
__device__ __forceinline__ float bf2f(ushort_t h) {
    unsigned u = ((unsigned)h) << 16;
    return __builtin_bit_cast(float, u);
}

// Per-block redundant BN reduce: Pv holds f32x2{sum,sq} [32][1024]; 8 threads/channel.
__device__ __forceinline__ void bn_reduce(const float* __restrict__ Pv,
                                          const float* __restrict__ gamma,
                                          const float* __restrict__ beta,
                                          float* sprm, int tid)
{
    int c = tid >> 3, l8 = tid & 7;
    const f32x2* base = (const f32x2*)(Pv + (size_t)c * 2 * NSLOT);
    float s = 0.f, q = 0.f;
    for (int k = 0; k < 128; ++k) {
        f32x2 v = base[l8 + (k << 3)];
        s += v[0]; q += v[1];
    }
#pragma unroll
    for (int m = 1; m < 8; m <<= 1) { s += __shfl_xor(s, m); q += __shfl_xor(q, m); }
    if (l8 == 0) {
        const float n = (float)(NIMG * HW);
        float mu  = s / n;
        float var = q / n - mu * mu;
        float a   = gamma[c] * rsqrtf(var + 1e-5f);
        sprm[c]        = a;
        sprm[COUT + c] = beta[c] - mu * a;
    }
}

// One conv phase for (img, tile). MODE 0: plane-major fp32 x, K=[xh;xl] vs A=[wh;wh].
// MODE 1: pixel-major bf16 in with BN1 affine+leaky from sprm. STORE: write bf16 out.
// acc keeps biased fp32 result live. Writes f32x2 BN partials to Pv.
template <int MODE, bool STORE>
__device__ __forceinline__ void conv_phase(
    const float* __restrict__ inf, const ushort_t* __restrict__ inh,
    const ushort_t* __restrict__ Wf, const float* __restrict__ bk,
    const float* sprm, ushort_t* __restrict__ tout, float* __restrict__ Pv,
    ushort_t* lds, float (*redS)[COUT], float (*redQ)[COUT],
    int img, int tileid, int tid, f32x4 (&acc)[4][2])
{
    const int tx   = (tileid & 7) * TIL;
    const int ty   = (tileid >> 3) * TIL;
    const int lane = tid & 63;
    const int wid  = tid >> 6;
    const int rxl  = lane & 15;
    const int cq   = lane >> 4;

    if (MODE == 0) {
#pragma unroll
        for (int e = 0; e < 4; ++e) {
            int task = e * 256 + tid;
            if (task < 800) {
                int h  = task >= 400 ? 1 : 0;
                int p  = task - h * 400;
                int ry = p / LP, rx = p - ry * LP;
                int gh = ty + ry - HALO, gw = tx + rx - HALO;
                bool ok = (unsigned)gh < (unsigned)HH && (unsigned)gw < (unsigned)WW;
                int ghc = min(max(gh, 0), HH - 1), gwc = min(max(gw, 0), WW - 1);
                const float* base = inf + (((size_t)(img >> 3) * CIN + 8 * h) * FF + (img & 7)) * HW
                                       + ghc * WW + gwc;
                short8 hi8, lo8;
#pragma unroll
                for (int cc = 0; cc < 8; ++cc) {
                    float v = base[(size_t)cc * FF * HW];
                    v = ok ? v : 0.f;
                    ushort_t hi = f2bf(v);
                    hi8[cc] = (short)hi;
                    lo8[cc] = (short)f2bf(v - bf2f(hi));
                }
                int swz = (p & 3) ^ ((p >> 2) & 3);
                *(short8*)&lds[p * 32 + 8 * (h ^ swz)]       = hi8;
                *(short8*)&lds[p * 32 + 8 * ((2 + h) ^ swz)] = lo8;
            }
        }
    } else {
#pragma unroll
        for (int e = 0; e < 7; ++e) {
            int task = e * 256 + tid;
            if (task < 1600) {
                int g  = task & 3, p = task >> 2;
                int ry = p / LP, rx = p - ry * LP;
                int gh = ty + ry - HALO, gw = tx + rx - HALO;
                bool ok = (unsigned)gh < (unsigned)HH && (unsigned)gw < (unsigned)WW;
                int ghc = min(max(gh, 0), HH - 1), gwc = min(max(gw, 0), WW - 1);
                const ushort_t* px = inh + ((size_t)img * HW + ghc * WW + gwc) * 32 + 8 * g;
                short8 raw = *(const short8*)px;
                short8 hv;
#pragma unroll
                for (int jj = 0; jj < 8; ++jj) {
                    int c = 8 * g + jj;
                    float v = bf2f((ushort_t)raw[jj]);
                    v = leaky(fmaf(sprm[c], v, sprm[COUT + c]));
                    hv[jj] = (short)f2bf(ok ? v : 0.f);
                }
                int swz = (p & 3) ^ ((p >> 2) & 3);
                *(short8*)&lds[p * 32 + 8 * (g ^ swz)] = hv;
            }
        }
    }
    __syncthreads();

#pragma unroll
    for (int ng = 0; ng < 4; ++ng)
#pragma unroll
        for (int oh = 0; oh < 2; ++oh) acc[ng][oh] = f32x4{0.f, 0.f, 0.f, 0.f};

    int q0[4];
#pragma unroll
    for (int ng = 0; ng < 4; ++ng) q0[ng] = (wid * 4 + ng + HALO) * LP + (rxl + HALO);

    const ushort_t* wl = Wf + (size_t)lane * 8;

#pragma unroll 1
    for (int n = 0; n < 17; ++n) {
        short8 A0 = *(const short8*)(wl + (size_t)(n * 2 + 0) * 512);
        short8 A1 = *(const short8*)(wl + (size_t)(n * 2 + 1) * 512);
        int dof = DOFF[n];
#pragma unroll
        for (int ng = 0; ng < 4; ++ng) {
            int p   = q0[ng] + dof;
            int swz = (p & 3) ^ ((p >> 2) & 3);
            short8 Bv = *(const short8*)&lds[p * 32 + 8 * (cq ^ swz)];
            acc[ng][0] = __builtin_amdgcn_mfma_f32_16x16x32_bf16(A0, Bv, acc[ng][0], 0, 0, 0);
            acc[ng][1] = __builtin_amdgcn_mfma_f32_16x16x32_bf16(A1, Bv, acc[ng][1], 0, 0, 0);
        }
    }

    float ssum[2][4], ssq[2][4];
#pragma unroll
    for (int oh = 0; oh < 2; ++oh)
#pragma unroll
        for (int rr = 0; rr < 4; ++rr) {
            float b = bk[oh * 16 + cq * 4 + rr];
#pragma unroll
            for (int ng = 0; ng < 4; ++ng) acc[ng][oh][rr] += b;
            ssum[oh][rr] = 0.f; ssq[oh][rr] = 0.f;
        }

#pragma unroll
    for (int ng = 0; ng < 4; ++ng) {
        int gh = ty + wid * 4 + ng, gw = tx + rxl;
        size_t pxb = ((size_t)img * HW + gh * WW + gw) * 32;
#pragma unroll
        for (int oh = 0; oh < 2; ++oh) {
            sh4 sv;
#pragma unroll
            for (int rr = 0; rr < 4; ++rr) {
                float v = acc[ng][oh][rr];
                sv[rr] = (short)f2bf(v);
                ssum[oh][rr] += v;
                ssq[oh][rr]   = fmaf(v, v, ssq[oh][rr]);
            }
            if (STORE) *(sh4*)&tout[pxb + oh * 16 + cq * 4] = sv;
        }
    }

#pragma unroll
    for (int oh = 0; oh < 2; ++oh)
#pragma unroll
        for (int rr = 0; rr < 4; ++rr) {
            float s = ssum[oh][rr], q = ssq[oh][rr];
#pragma unroll
            for (int m = 1; m < 16; m <<= 1) { s += __shfl_xor(s, m); q += __shfl_xor(q, m); }
            if (rxl == 0) {
                redS[wid][oh * 16 + cq * 4 + rr] = s;
                redQ[wid][oh * 16 + cq * 4 + rr] = q;
            }
        }
    __syncthreads();

    const int slot = img * 64 + tileid;
    if (tid < COUT) {
        float s = redS[0][tid] + redS[1][tid] + redS[2][tid] + redS[3][tid];
        float q = redQ[0][tid] + redQ[1][tid] + redQ[2][tid] + redQ[3][tid];
        ((f32x2*)Pv)[(size_t)tid * NSLOT + slot] = f32x2{s, q};
    }
}

// ---------------- fused cooperative kernel ----------------
__global__ __launch_bounds__(256, 4)
void fused(const float* __restrict__ x,  const float* __restrict__ W1,
           const float* __restrict__ b1, const float* __restrict__ g1,
           const float* __restrict__ be1, const float* __restrict__ W2,
           const float* __restrict__ b2, const float* __restrict__ g2,
           const float* __restrict__ be2, float* __restrict__ out,
           ushort_t* __restrict__ t1, float* __restrict__ Pv1,
           float* __restrict__ Pv2, ushort_t* __restrict__ Wf1,
           ushort_t* __restrict__ Wf2)
{
    cg::grid_group grid = cg::this_grid();

    __shared__ __align__(16) ushort_t lds[NPX * 32];
    __shared__ float redS[4][COUT], redQ[4][COUT];
    __shared__ float sprm[2 * COUT];

    const int tid    = threadIdx.x;
    const int tileid = blockIdx.x;
    const int img    = blockIdx.y;
    const int bid    = img * 64 + tileid;

    if (bid < 2 * WFN / 256) {
        int idx   = bid * 256 + tid;
        int which = idx >= WFN;
        int sub   = which ? idx - WFN : idx;
        const float* W = which ? W2 : W1;
        ushort_t* Wf   = which ? Wf2 : Wf1;
        int ci         = which ? COUT : CIN;
        int j  = sub & 7;
        int l  = (sub >> 3) & 63;
        int oh = (sub >> 9) & 1;
        int n  = sub >> 10;
        int oc = oh * 16 + (l & 15);
        int k  = ((l >> 4) << 3) + j;
        int c  = which ? k : (k & 15);
        const float* wp = W + ((size_t)oc * ci + c) * 16;
        float v;
        if (n < 16) v = -wp[n];
        else { v = 0.f; for (int q = 0; q < 16; ++q) v += wp[q]; }
        Wf[sub] = f2bf(v);
    }
    __threadfence();
    grid.sync();
    __threadfence();

    f32x4 acc[4][2];
    conv_phase<0, true>(x, nullptr, Wf1, b1, nullptr, t1, Pv1,
                        lds, redS, redQ, img, tileid, tid, acc);
    __threadfence();
    grid.sync();
    __threadfence();

    bn_reduce(Pv1, g1, be1, sprm, tid);
    __syncthreads();

    conv_phase<1, false>(nullptr, t1, Wf2, b2, sprm, nullptr, Pv2,
                         lds, redS, redQ, img, tileid, tid, acc);
    __threadfence();
    grid.sync();
    __threadfence();

    bn_reduce(Pv2, g2, be2, sprm, tid);
    __syncthreads();

    const int lane = tid & 63, wid = tid >> 6;
    const int rxl  = lane & 15, cq = lane >> 4;
    const int tx   = (tileid & 7) * TIL, ty = (tileid >> 3) * TIL;
    const int b    = img >> 3;
    const int obase = (img & 7) * 4;
#pragma unroll
    for (int ng = 0; ng < 4; ++ng) {
        int gh = ty + wid * 4 + ng, gw = tx + rxl;
#pragma unroll
        for (int oh = 0; oh < 2; ++oh) {
            float s = 0.f;
#pragma unroll
            for (int rr = 0; rr < 4; ++rr) {
                int c = oh * 16 + cq * 4 + rr;
                s += leaky(fmaf(sprm[c], acc[ng][oh][rr], sprm[COUT + c]));
            }
            s += __shfl_xor(s, 16);
            if ((cq & 1) == 0) {
                int o = obase + oh * 2 + (cq >> 1);
                out[((size_t)b * COUT + o) * HW + gh * WW + gw] = 0.125f * s;
            }
        }
    }
}

// ---------------- fallback kernels ----------------
__global__ __launch_bounds__(256)
void prep_weights(const float* __restrict__ W1, const float* __restrict__ W2,
                  ushort_t* __restrict__ Wf1, ushort_t* __restrict__ Wf2)
{
    int which = blockIdx.y;
    const float* W = which ? W2 : W1;
    ushort_t* Wf   = which ? Wf2 : Wf1;
    int ci         = which ? COUT : CIN;
    int idx = blockIdx.x * 256 + threadIdx.x;
    int j  = idx & 7;
    int l  = (idx >> 3) & 63;
    int oh = (idx >> 9) & 1;
    int n  = idx >> 10;
    int oc = oh * 16 + (l & 15);
    int k  = ((l >> 4) << 3) + j;
    int c  = which ? k : (k & 15);
    const float* wp = W + ((size_t)oc * ci + c) * 16;
    float v;
    if (n < 16) v = -wp[n];
    else { v = 0.f; for (int q = 0; q < 16; ++q) v += wp[q]; }
    Wf[idx] = f2bf(v);
}

__global__ __launch_bounds__(256)
void conv1_k(const float* __restrict__ x, const ushort_t* __restrict__ Wf1,
             const float* __restrict__ b1, ushort_t* __restrict__ t1,
             float* __restrict__ Pv1)
{
    __shared__ __align__(16) ushort_t lds[NPX * 32];
    __shared__ float redS[4][COUT], redQ[4][COUT];
    f32x4 acc[4][2];
    conv_phase<0, true>(x, nullptr, Wf1, b1, nullptr, t1, Pv1,
                        lds, redS, redQ, blockIdx.y, blockIdx.x, threadIdx.x, acc);
}

__global__ __launch_bounds__(256)
void conv2_k(const ushort_t* __restrict__ t1, const ushort_t* __restrict__ Wf2,
             const float* __restrict__ b2, const float* __restrict__ Pv1,
             const float* __restrict__ g1, const float* __restrict__ be1,
             ushort_t* __restrict__ t2, float* __restrict__ Pv2)
{
    __shared__ __align__(16) ushort_t lds[NPX * 32];
    __shared__ float redS[4][COUT], redQ[4][COUT];
    __shared__ float sprm[2 * COUT];
    bn_reduce(Pv1, g1, be1, sprm, threadIdx.x);
    __syncthreads();
    f32x4 acc[4][2];
    conv_phase<1, true>(nullptr, t1, Wf2, b2, sprm, t2, Pv2,
                        lds, redS, redQ, blockIdx.y, blockIdx.x, threadIdx.x, acc);
}

__global__ __launch_bounds__(256)
void finalize_k(const ushort_t* __restrict__ t2, const float* __restrict__ Pv2,
                const float* __restrict__ g2, const float* __restrict__ be2,
                float* __restrict__ outp)
{
    __shared__ float sprm[2 * COUT];
    bn_reduce(Pv2, g2, be2, sprm, threadIdx.x);
    __syncthreads();
    int base = blockIdx.x * 1024;
#pragma unroll
    for (int e = 0; e < 4; ++e) {
        int gid  = base + e * 256 + threadIdx.x;
        int p    = gid & (HW - 1);
        int rest = gid >> 14;
        int o    = rest & 31;
        int b    = rest >> 5;
        int img  = b * 8 + (o >> 2);
        int cb   = (o & 3) * 8;
        const ushort_t* px = t2 + ((size_t)img * HW + p) * 32 + cb;
        short8 raw = *(const short8*)px;
        float s = 0.f;
#pragma unroll
        for (int j = 0; j < 8; ++j) {
            int c = cb + j;
            float v = bf2f((ushort_t)raw[j]);
            s += leaky(fmaf(sprm[c], v, sprm[COUT + c]));
        }
        outp[gid] = 0.125f * s;
    }
}

extern "C" void kernel_launch(void* const* d_in, const int* in_sizes, int n_in,
                              void* d_out, int out_size, void* d_ws, size_t ws_size,
                              hipStream_t stream)
{
    const float* x   = (const float*)d_in[0];
    const float* W1  = (const float*)d_in[1];
    const float* b1  = (const float*)d_in[2];
    const float* g1  = (const float*)d_in[3];
    const float* be1 = (const float*)d_in[4];
    const float* W2  = (const float*)d_in[5];
    const float* b2  = (const float*)d_in[6];
    const float* g2  = (const float*)d_in[7];
    const float* be2 = (const float*)d_in[8];
    float* out = (float*)d_out;

    const size_t TSZH = (size_t)NIMG * HW * 32;    // 8388608 bf16 elems (16 MB)
    ushort_t* t1   = (ushort_t*)d_ws;
    ushort_t* t2   = t1 + TSZH;
    float*    Pv1  = (float*)(t2 + TSZH);          // f32x2 [32][1024]
    float*    Pv2  = Pv1 + 2 * COUT * NSLOT;
    ushort_t* Wf1  = (ushort_t*)(Pv2 + 2 * COUT * NSLOT);
    ushort_t* Wf2  = Wf1 + WFN;

    // capture-safe host queries: is a 1024-block cooperative launch co-resident?
    int dev = 0;
    hipGetDevice(&dev);
    int coopAttr = 0;
    hipDeviceGetAttribute(&coopAttr, hipDeviceAttributeCooperativeLaunch, dev);
    int maxB = 0;
    hipOccupancyMaxActiveBlocksPerMultiprocessor(&maxB, (const void*)fused, 256, 0);

    bool coop_done = false;
    if (coopAttr && maxB >= 4) {
        void* args[] = { (void*)&x,  (void*)&W1, (void*)&b1, (void*)&g1, (void*)&be1,
                         (void*)&W2, (void*)&b2, (void*)&g2, (void*)&be2,
                         (void*)&out, (void*)&t1, (void*)&Pv1, (void*)&Pv2,
                         (void*)&Wf1, (void*)&Wf2 };
        hipError_t e = hipLaunchCooperativeKernel((const void*)fused, dim3(64, NIMG),
                                                  dim3(256), args, 0, stream);
        coop_done = (e == hipSuccess);
    }
    if (!coop_done) {
        dim3 pg(WFN / 256, 2);
        prep_weights<<<pg, 256, 0, stream>>>(W1, W2, Wf1, Wf2);
        dim3 cg_(64, NIMG);
        conv1_k<<<cg_, 256, 0, stream>>>(x, Wf1, b1, t1, Pv1);
        conv2_k<<<cg_, 256, 0, stream>>>(t1, Wf2, b2, Pv1, g1, be1, t2, Pv2);
        finalize_k<<<(BB * COUT * HW) / 1024, 256, 0, stream>>>(t2, Pv2, g2, be2, out);
    }
}